// Round 5
// baseline (176.308 us; speedup 1.0000x reference)
//
#include <hip/hip_runtime.h>
#include <hip/hip_fp16.h>
#include <math.h>

#define DIM  64
#define SPAN 256            // nodes per bucket (dst>>8)
#define NBIN 256            // binning blocks (private (block,bucket) segments)
#define KMAX 512            // max buckets (N <= 131072)
#define CAP  6144           // LDS staging capacity per bucket (48 KB)

// ---------------- Kernel 1: per-node scores + fp16 x copy ------------------
// One wave per node. Emits xh while x row is already in registers.
__global__ void score_kernel(const float* __restrict__ x,
                             const float* __restrict__ w_src,
                             const float* __restrict__ w_dst,
                             float* __restrict__ a_src,
                             float* __restrict__ a_dst,
                             __half* __restrict__ xh,
                             int N) {
    int gid  = blockIdx.x * blockDim.x + threadIdx.x;
    int node = gid >> 6;
    int lane = threadIdx.x & 63;
    if (node >= N) return;
    float xv = x[(size_t)node * DIM + lane];
    xh[(size_t)node * DIM + lane] = __float2half_rn(xv);
    float s1 = xv * w_src[lane];
    float s2 = xv * w_dst[lane];
    #pragma unroll
    for (int off = 32; off > 0; off >>= 1) {
        s1 += __shfl_down(s1, off, 64);
        s2 += __shfl_down(s2, off, 64);
    }
    if (lane == 0) {
        a_src[node] = s1;
        a_dst[node] = s2;
    }
}

// ---------------- Kernel 2: coarse histogram matrix ------------------------
// cnt[bucket * NBIN + block] = #edges of bucket seen by block. Deterministic.
__global__ __launch_bounds__(1024) void hist_coarse(
        const int* __restrict__ dst, int* __restrict__ cnt,
        int E, int N, int K) {
    __shared__ int lh[KMAX];
    int tid = threadIdx.x;
    for (int j = tid; j < K; j += blockDim.x) lh[j] = 0;
    __syncthreads();
    for (int base = blockIdx.x * 1024; base < E; base += NBIN * 1024) {
        int e = base + tid;
        if (e < E) {
            unsigned t = (unsigned)dst[e];
            if (t >= (unsigned)N) t = 0;          // guard
            atomicAdd(&lh[t >> 8], 1);
        }
    }
    __syncthreads();
    for (int j = tid; j < K; j += blockDim.x)
        cnt[j * NBIN + blockIdx.x] = lh[j];
}

// ---------------- Kernels 3-4: exclusive scan (double-buffered HS) ---------
// scan_part is in-place safe (stages into LDS before any write).
__global__ void scan_part(const int* __restrict__ cnt, int* __restrict__ offs,
                          int* __restrict__ bsum, int N) {
    __shared__ int buf[2][256];
    int tid = threadIdx.x;
    int i = blockIdx.x * 256 + tid;
    int v = (i < N) ? cnt[i] : 0;
    int sel = 0;
    buf[0][tid] = v;
    __syncthreads();
    for (int off = 1; off < 256; off <<= 1) {
        int nsel = sel ^ 1;
        buf[nsel][tid] = buf[sel][tid] + ((tid >= off) ? buf[sel][tid - off] : 0);
        __syncthreads();
        sel = nsel;
    }
    if (i < N) offs[i] = buf[sel][tid] - v;
    if (tid == 255) bsum[blockIdx.x] = buf[sel][255];
}

__global__ void scan_top(int* __restrict__ bsum, int* __restrict__ offs,
                         int NB, int N) {
    __shared__ int buf[2][512];
    int tid = threadIdx.x;
    int v = (tid < NB) ? bsum[tid] : 0;
    int sel = 0;
    buf[0][tid] = v;
    __syncthreads();
    for (int off = 1; off < 512; off <<= 1) {
        int nsel = sel ^ 1;
        buf[nsel][tid] = buf[sel][tid] + ((tid >= off) ? buf[sel][tid - off] : 0);
        __syncthreads();
        sel = nsel;
    }
    if (tid < NB) bsum[tid] = buf[sel][tid] - v;
    if (tid == 511) offs[N] = buf[sel][511];      // grand total (unused)
}

// ---------------- Kernel 5: binpass — bucket-grouped payload ---------------
// Absolute offset = moffs[i] + bsum[i>>8] (base-add fused).
// pay = rec32<<32 | f32bits(a), rec32 = src<<8 | dst_local.
__global__ __launch_bounds__(1024) void binpass_kernel(
        const float* __restrict__ ew,
        const int* __restrict__ src_idx,
        const int* __restrict__ dst_idx,
        const float* __restrict__ a_src,
        const float* __restrict__ a_dst,
        const int* __restrict__ moffs,
        const int* __restrict__ bsum,
        unsigned long long* __restrict__ pay,
        int E, int N, int K) {
    __shared__ int lcur[KMAX];
    int tid = threadIdx.x;
    for (int j = tid; j < K; j += blockDim.x) {
        int i = j * NBIN + blockIdx.x;
        lcur[j] = moffs[i] + bsum[i >> 8];
    }
    __syncthreads();
    for (int base = blockIdx.x * 1024; base < E; base += NBIN * 1024) {
        int e = base + tid;
        if (e < E) {
            unsigned s = (unsigned)src_idx[e];
            unsigned t = (unsigned)dst_idx[e];
            if (s >= (unsigned)N) s = 0;          // guard
            if (t >= (unsigned)N) t = 0;          // guard
            float a = tanhf(a_src[s] + a_dst[t]) * ew[e];
            int bk = (int)(t >> 8);
            int pos = atomicAdd(&lcur[bk], 1);    // LDS cursor, block-local
            unsigned rec = (s << 8) | (t & 255u);
            pay[pos] = ((unsigned long long)rec << 32) |
                       (unsigned long long)__float_as_uint(a);
        }
    }
}

// ---------------- Kernel 6: fused per-bucket sort + gather -----------------
// Stage bucket in LDS, counting-sort an index array (no global writeback),
// then 16 waves gather. 4 edges per wave-load — lane (grp=lane>>4,
// sub=lane&15) loads 8B (4 halves) of row s[grp] at dim sub*4, butterfly
// reduce across the 4 groups at the end, lanes 0..15 store one float4.
__global__ __launch_bounds__(1024) void sort_gather_kernel(
        const __half* __restrict__ xh,
        const float* __restrict__ x32,
        const unsigned long long* __restrict__ pay,
        const int* __restrict__ moffs,
        const int* __restrict__ bsum,
        float* __restrict__ h,
        int N, int K, int E) {
    __shared__ unsigned long long srec[CAP];      // 48 KB
    __shared__ unsigned short sidx[CAP];          // 12 KB
    __shared__ int hcnt[SPAN];
    __shared__ int hoff[2][SPAN];
    __shared__ int lcur[SPAN];
    __shared__ int nstart[SPAN];
    int tid = threadIdx.x;
    int b   = blockIdx.x;
    int i0 = b * NBIN;
    int bstart = moffs[i0] + bsum[i0 >> 8];
    int bend;
    if (b == K - 1) bend = E;
    else { int i1 = (b + 1) * NBIN; bend = moffs[i1] + bsum[i1 >> 8]; }
    int cnt = bend - bstart;

    if (cnt <= CAP) {
        // ---- stage + histogram ----
        if (tid < SPAN) hcnt[tid] = 0;
        __syncthreads();
        for (int i = tid; i < cnt; i += 1024) {
            unsigned long long r = pay[bstart + i];
            srec[i] = r;
            atomicAdd(&hcnt[(int)((r >> 32) & 255u)], 1);
        }
        __syncthreads();
        // ---- inclusive scan of hcnt[256] ----
        int sel = 0;
        if (tid < SPAN) hoff[0][tid] = hcnt[tid];
        __syncthreads();
        for (int off = 1; off < SPAN; off <<= 1) {
            int nsel = sel ^ 1;
            if (tid < SPAN)
                hoff[nsel][tid] = hoff[sel][tid] +
                                  ((tid >= off) ? hoff[sel][tid - off] : 0);
            __syncthreads();
            sel = nsel;
        }
        if (tid < SPAN) {
            int excl = hoff[sel][tid] - hcnt[tid];
            nstart[tid] = excl;
            lcur[tid]   = excl;
        }
        __syncthreads();
        // ---- permute indices only (sidx), srec stays put ----
        for (int i = tid; i < cnt; i += 1024) {
            unsigned long long r = srec[i];
            int d = (int)((r >> 32) & 255u);
            int pos = atomicAdd(&lcur[d], 1);
            sidx[pos] = (unsigned short)i;
        }
        __syncthreads();
        // ---- gather phase: wave per node, 4 edges per load instruction ----
        int lane = tid & 63;
        int wave = tid >> 6;                      // 16 waves
        int grp  = lane >> 4;                     // edge slot 0..3
        int sub  = lane & 15;                     // dim quad: dims 4*sub..4*sub+3
        for (int d = wave; d < SPAN; d += 16) {
            int node = b * SPAN + d;
            if (node >= N) break;                 // only last bucket; d monotone
            int p  = nstart[d];
            int pe = p + hcnt[d];
            float ax = 0.f, ay = 0.f, az = 0.f, aw = 0.f;
            while (p + 8 <= pe) {
                unsigned long long r0 = srec[sidx[p + grp]];
                unsigned long long r1 = srec[sidx[p + 4 + grp]];
                p += 8;
                unsigned s0 = (unsigned)(r0 >> 40); if (s0 >= (unsigned)N) s0 = 0;
                unsigned s1 = (unsigned)(r1 >> 40); if (s1 >= (unsigned)N) s1 = 0;
                uint2 v0 = *(const uint2*)(xh + (size_t)s0 * DIM + (sub << 2));
                uint2 v1 = *(const uint2*)(xh + (size_t)s1 * DIM + (sub << 2));
                float a0 = __uint_as_float((unsigned)r0);
                float a1 = __uint_as_float((unsigned)r1);
                float2 l0 = __half22float2(*(const __half2*)&v0.x);
                float2 h0 = __half22float2(*(const __half2*)&v0.y);
                float2 l1 = __half22float2(*(const __half2*)&v1.x);
                float2 h1 = __half22float2(*(const __half2*)&v1.y);
                ax = fmaf(a0, l0.x, ax); ay = fmaf(a0, l0.y, ay);
                az = fmaf(a0, h0.x, az); aw = fmaf(a0, h0.y, aw);
                ax = fmaf(a1, l1.x, ax); ay = fmaf(a1, l1.y, ay);
                az = fmaf(a1, h1.x, az); aw = fmaf(a1, h1.y, aw);
            }
            while (p < pe) {
                int q = p + grp;
                float a0 = 0.f;
                unsigned s0 = 0;
                if (q < pe) {
                    unsigned long long r0 = srec[sidx[q]];
                    a0 = __uint_as_float((unsigned)r0);
                    s0 = (unsigned)(r0 >> 40); if (s0 >= (unsigned)N) s0 = 0;
                }
                p += 4;
                uint2 v0 = *(const uint2*)(xh + (size_t)s0 * DIM + (sub << 2));
                float2 l0 = __half22float2(*(const __half2*)&v0.x);
                float2 h0 = __half22float2(*(const __half2*)&v0.y);
                ax = fmaf(a0, l0.x, ax); ay = fmaf(a0, l0.y, ay);
                az = fmaf(a0, h0.x, az); aw = fmaf(a0, h0.y, aw);
            }
            // butterfly reduce across the 4 edge-groups (lanes ^16, ^32)
            ax += __shfl_xor(ax, 16, 64); ay += __shfl_xor(ay, 16, 64);
            az += __shfl_xor(az, 16, 64); aw += __shfl_xor(aw, 16, 64);
            ax += __shfl_xor(ax, 32, 64); ay += __shfl_xor(ay, 32, 64);
            az += __shfl_xor(az, 32, 64); aw += __shfl_xor(aw, 32, 64);
            if (grp == 0) {
                float4 out = make_float4(ax, ay, az, aw);
                *(float4*)(h + (size_t)node * DIM + (sub << 2)) = out;
            }
        }
    } else {
        // ---- slow path (cnt > CAP, never for this input): atomic accumulate
        for (int j = tid; j < SPAN * DIM; j += 1024) {
            int node = b * SPAN + (j >> 6);
            if (node < N) h[(size_t)node * DIM + (j & 63)] = 0.f;
        }
        __syncthreads();
        for (int i = tid; i < cnt; i += 1024) {
            unsigned long long r = pay[bstart + i];
            unsigned s = (unsigned)(r >> 40);
            if (s >= (unsigned)N) s = 0;
            int node = b * SPAN + (int)((r >> 32) & 255u);
            float a = __uint_as_float((unsigned)r);
            if (node < N)
                for (int k = 0; k < DIM; ++k)
                    atomicAdd(&h[(size_t)node * DIM + k],
                              a * x32[(size_t)s * DIM + k]);
        }
    }
}

// ---------------- Fallback (round-1 atomic path, known-good) ---------------
__global__ void zero_h_kernel(float* __restrict__ p, int n) {
    int i = blockIdx.x * blockDim.x + threadIdx.x;
    if (i < n) p[i] = 0.f;
}

__global__ void edge_kernel_atomic(const float* __restrict__ x,
                                   const float* __restrict__ ew,
                                   const int* __restrict__ src_idx,
                                   const int* __restrict__ dst_idx,
                                   const float* __restrict__ a_src,
                                   const float* __restrict__ a_dst,
                                   float* __restrict__ h,
                                   int E) {
    int gid  = blockIdx.x * blockDim.x + threadIdx.x;
    int e    = gid >> 6;
    int lane = threadIdx.x & 63;
    if (e >= E) return;
    int s = src_idx[e];
    int t = dst_idx[e];
    float a  = tanhf(a_src[s] + a_dst[t]) * ew[e];
    float xv = x[(size_t)s * DIM + lane];
    atomicAdd(&h[(size_t)t * DIM + lane], a * xv);
}

// Plain score (no xh) for the fallback tier.
__global__ void score_only_kernel(const float* __restrict__ x,
                                  const float* __restrict__ w_src,
                                  const float* __restrict__ w_dst,
                                  float* __restrict__ a_src,
                                  float* __restrict__ a_dst,
                                  int N) {
    int gid  = blockIdx.x * blockDim.x + threadIdx.x;
    int node = gid >> 6;
    int lane = threadIdx.x & 63;
    if (node >= N) return;
    float xv = x[(size_t)node * DIM + lane];
    float s1 = xv * w_src[lane];
    float s2 = xv * w_dst[lane];
    #pragma unroll
    for (int off = 32; off > 0; off >>= 1) {
        s1 += __shfl_down(s1, off, 64);
        s2 += __shfl_down(s2, off, 64);
    }
    if (lane == 0) {
        a_src[node] = s1;
        a_dst[node] = s2;
    }
}

extern "C" void kernel_launch(void* const* d_in, const int* in_sizes, int n_in,
                              void* d_out, int out_size, void* d_ws, size_t ws_size,
                              hipStream_t stream) {
    const float* x     = (const float*)d_in[0];
    const float* w_src = (const float*)d_in[1];
    const float* w_dst = (const float*)d_in[2];
    const float* ew    = (const float*)d_in[3];
    const int*   src   = (const int*)d_in[4];
    const int*   dst   = (const int*)d_in[5];
    float* h = (float*)d_out;

    int N = in_sizes[0] / DIM;
    int E = in_sizes[3];

    int K    = (N + SPAN - 1) / SPAN;     // buckets
    int Ntot = K * NBIN;                  // count-matrix entries
    int NBs  = (Ntot + 255) / 256;        // scan blocks

    // ws layout (4B units):
    // [a_src N][a_dst N][moffs Ntot+1][bsum NBs][pad][pay E*8B][xh N*DIM*2B]
    float* a_src  = (float*)d_ws;
    float* a_dst  = a_src + N;
    int*   moffs  = (int*)(a_dst + N);
    int*   bsum   = moffs + Ntot + 1;
    size_t head_bytes = ((size_t)(2 * N) + (size_t)Ntot + 1 + (size_t)NBs) * 4;
    size_t pay_off = (head_bytes + 15) & ~(size_t)15;
    unsigned long long* pay = (unsigned long long*)((char*)d_ws + pay_off);
    size_t xh_off = pay_off + (size_t)E * 8;
    __half* xh = (__half*)((char*)d_ws + xh_off);
    size_t need = xh_off + (size_t)N * DIM * 2;

    int score_blocks = (N + 3) / 4;

    if (ws_size < need || K > KMAX || NBs > 512 || (N * DIM) % 2 != 0) {
        // fallback: round-1 atomic path
        score_only_kernel<<<score_blocks, 256, 0, stream>>>(x, w_src, w_dst,
                                                            a_src, a_dst, N);
        int ob = (out_size + 255) / 256;
        zero_h_kernel<<<ob, 256, 0, stream>>>(h, out_size);
        int edge_blocks = (E + 3) / 4;
        edge_kernel_atomic<<<edge_blocks, 256, 0, stream>>>(x, ew, src, dst,
                                                            a_src, a_dst, h, E);
        return;
    }

    score_kernel<<<score_blocks, 256, 0, stream>>>(x, w_src, w_dst,
                                                   a_src, a_dst, xh, N);
    hist_coarse<<<NBIN, 1024, 0, stream>>>(dst, moffs, E, N, K);
    scan_part<<<NBs, 256, 0, stream>>>(moffs, moffs, bsum, Ntot);
    scan_top<<<1, 512, 0, stream>>>(bsum, moffs, NBs, Ntot);
    binpass_kernel<<<NBIN, 1024, 0, stream>>>(ew, src, dst, a_src, a_dst,
                                              moffs, bsum, pay, E, N, K);
    sort_gather_kernel<<<K, 1024, 0, stream>>>(xh, x, pay, moffs, bsum,
                                               h, N, K, E);
}